// Round 13
// baseline (2152.458 us; speedup 1.0000x reference)
//
#include <hip/hip_runtime.h>

#define DEV __device__ __forceinline__

typedef __attribute__((ext_vector_type(4))) float f32x4;
typedef __attribute__((ext_vector_type(8))) short short8_t;

constexpr int LNUM = 6;
constexpr int BB = 4;
constexpr int SS = 1024;
constexpr int DD = 1024;
constexpr int HH = 16;
constexpr int HDD = 64;
constexpr int FF = 4096;
constexpr int VV = 32000;
constexpr int MROWS = BB * SS;   // 4096

DEV short f2bf(float f) {
  union { float f; unsigned u; } x; x.f = f;
  unsigned r = x.u + 0x7fffu + ((x.u >> 16) & 1u);   // RNE
  return (short)(r >> 16);
}

DEV float bf2f(short s) {
  union { unsigned u; float f; } x;
  x.u = ((unsigned)(unsigned short)s) << 16;
  return x.f;
}

#define BAR() do { __builtin_amdgcn_sched_barrier(0); \
  __builtin_amdgcn_s_barrier(); \
  __builtin_amdgcn_sched_barrier(0); } while (0)

// ---------------- embedding: x = tok_emb[tok] + pos_emb ----------------
__global__ __launch_bounds__(256) void k_embed(
    const int* __restrict__ tok, const float* __restrict__ te,
    const float* __restrict__ pe, float* __restrict__ xf,
    short* __restrict__ xb) {
  int i = blockIdx.x * 256 + threadIdx.x;            // over MROWS*DD/4
  int bs = i >> 8, d4 = i & 255;
  int t = tok[bs];
  float4 a = ((const float4*)(te + (size_t)t * DD))[d4];
  float4 b = ((const float4*)(pe + (size_t)(bs & (SS - 1)) * DD))[d4];
  float4 r; r.x = a.x + b.x; r.y = a.y + b.y; r.z = a.z + b.z; r.w = a.w + b.w;
  ((float4*)xf)[i] = r;
  short4 o; o.x = f2bf(r.x); o.y = f2bf(r.y); o.z = f2bf(r.z); o.w = f2bf(r.w);
  ((short4*)xb)[i] = o;
}

// ---- vectorized transpose+cvt: W[K,N] -> Wt[N,K] bf16, 64x64 tiles ----
__global__ __launch_bounds__(256) void k_tcvt4(
    const float* __restrict__ in, short* __restrict__ out, int K, int N,
    long long istride, long long ostride) {
  __shared__ float tile[64][65];
  const float* ip = in + (size_t)blockIdx.z * istride;
  short* op = out + (size_t)blockIdx.z * ostride;
  const int bn = blockIdx.x * 64, bk = blockIdx.y * 64;
  const int tc = threadIdx.x & 15, tr = threadIdx.x >> 4;  // 16 col4 x 16 rows
  #pragma unroll
  for (int i = 0; i < 4; i++) {
    const int r = tr + 16 * i;
    float4 v = *(const float4*)&ip[(size_t)(bk + r) * N + bn + tc * 4];
    tile[r][tc * 4 + 0] = v.x; tile[r][tc * 4 + 1] = v.y;
    tile[r][tc * 4 + 2] = v.z; tile[r][tc * 4 + 3] = v.w;
  }
  __syncthreads();
  #pragma unroll
  for (int i = 0; i < 4; i++) {
    const int wr = tr + 16 * i;           // output row (n)
    short4 s;
    s.x = f2bf(tile[tc * 4 + 0][wr]);
    s.y = f2bf(tile[tc * 4 + 1][wr]);
    s.z = f2bf(tile[tc * 4 + 2][wr]);
    s.w = f2bf(tile[tc * 4 + 3][wr]);
    *(short4*)&op[(size_t)(bn + wr) * K + bk + tc * 4] = s;
  }
}

// ---- same, 3-source merged q/k/v: z = l*3 + which, dst [L][3][D][D] ----
__global__ __launch_bounds__(256) void k_tcvt4q(
    const float* __restrict__ Wq, const float* __restrict__ Wk,
    const float* __restrict__ Wv, short* __restrict__ out) {
  __shared__ float tile[64][65];
  const int z = blockIdx.z, l = z / 3, which = z - l * 3;
  const float* ip = (which == 0 ? Wq : which == 1 ? Wk : Wv)
                    + (size_t)l * DD * DD;
  short* op = out + (size_t)z * DD * DD;
  const int bn = blockIdx.x * 64, bk = blockIdx.y * 64;
  const int tc = threadIdx.x & 15, tr = threadIdx.x >> 4;
  #pragma unroll
  for (int i = 0; i < 4; i++) {
    const int r = tr + 16 * i;
    float4 v = *(const float4*)&ip[(size_t)(bk + r) * DD + bn + tc * 4];
    tile[r][tc * 4 + 0] = v.x; tile[r][tc * 4 + 1] = v.y;
    tile[r][tc * 4 + 2] = v.z; tile[r][tc * 4 + 3] = v.w;
  }
  __syncthreads();
  #pragma unroll
  for (int i = 0; i < 4; i++) {
    const int wr = tr + 16 * i;
    short4 s;
    s.x = f2bf(tile[tc * 4 + 0][wr]);
    s.y = f2bf(tile[tc * 4 + 1][wr]);
    s.z = f2bf(tile[tc * 4 + 2][wr]);
    s.w = f2bf(tile[tc * 4 + 3][wr]);
    *(short4*)&op[(size_t)(bn + wr) * DD + bk + tc * 4] = s;
  }
}

DEV void gload16(const short* g, short* l) {
  __builtin_amdgcn_global_load_lds(
      (const __attribute__((address_space(1))) void*)g,
      (__attribute__((address_space(3))) void*)l, 16, 0, 0);
}

// ====== 128x128 dbuf-counted bf16 GEMM (BK=64, 2 blocks/CU) ======
// Round-12's winner, now the only GEMM body. stage(t+1) into the OTHER
// buffer at window top; 16 ds_reads + 32 MFMA of tile t; vmcnt(0)+BAR
// gates tile t+1. 64 KiB LDS -> 2 blocks/CU (co-resident block covers
// residual stalls, m114). 128B rows -> proven (row&7)<<4 swizzle (rule #21).
// SWZ=1: m204-bijective XCD swizzle, B-panel-major chunks (consecutive lid
// share bx -> per-XCD B-panel L2 reuse). Requires gridDim.y==32, nwg%8==0.
// MODEs: 6 relu+bias->bf16; 8 QKV scatter; 9 fp32+bias; 15 bf16; 17 bf16+bias.
template<int MODE, int SWZ>
DEV void gemm128db_body(short* lds,
    const short* __restrict__ A, const short* __restrict__ Bt,
    const float* __restrict__ bias, void* __restrict__ Cp,
    int M, int N, int K, int lda, int ldb) {
  const int tid = threadIdx.x;
  int bx = blockIdx.x, by = blockIdx.y;
  if (SWZ) {
    const int nbx = gridDim.x;
    const int nwg = nbx << 5;               // gridDim.y == 32
    const int hid = by * nbx + bx;
    const int cpx = nwg >> 3;
    const int lid = (hid & 7) * cpx + (hid >> 3);
    by = lid & 31; bx = lid >> 5;
  }
  const int n0 = bx * 128, m0 = by * 128;
  const int lane = tid & 63;
  const int wid = tid >> 6;                 // 4 waves: 2M x 2N
  const int wm = wid >> 1, wn = wid & 1;
  const int l16 = lane & 15, kg = lane >> 4;
  const int xorv = (l16 & 7) << 4;
  const int cs[2] = { ((kg << 4) ^ xorv) >> 1,
                      ((64 | (kg << 4)) ^ xorv) >> 1 };
  const int rr = tid >> 3;                  // 0..31 (8 thr/row)
  const int sce = ((((tid & 7) << 4) ^ ((rr & 7) << 4)) >> 1);
  const int ldst = (tid & ~63) * 8;         // wave-uniform elem base

  const int NT = K >> 6;

  auto stage = [&](int t2, int c2) {
    const int k0 = t2 << 6;
    const int base = c2 * 16384;            // buf = 16384 shorts (A 8K | B 8K)
    #pragma unroll
    for (int i = 0; i < 4; i++)
      gload16(A + (size_t)(m0 + i * 32 + rr) * lda + k0 + sce,
              &lds[base + i * 2048 + ldst]);
    #pragma unroll
    for (int i = 0; i < 4; i++)
      gload16(Bt + (size_t)(n0 + i * 32 + rr) * ldb + k0 + sce,
              &lds[base + 8192 + i * 2048 + ldst]);
  };

  f32x4 acc[4][4];
  #pragma unroll
  for (int a = 0; a < 4; a++)
    #pragma unroll
    for (int b = 0; b < 4; b++)
      #pragma unroll
      for (int j = 0; j < 4; j++) acc[a][b][j] = 0.f;

  stage(0, 0);
  asm volatile("s_waitcnt vmcnt(0)" ::: "memory");
  BAR();

  for (int t = 0; t < NT; t++) {
    const int c = t & 1;
    if (t + 1 < NT) stage(t + 1, c ^ 1);    // other buffer: no in-window hazard
    const int ab = c * 16384;
    short8_t a[4][2], b[4][2];
    #pragma unroll
    for (int mi = 0; mi < 4; mi++)
      #pragma unroll
      for (int kk = 0; kk < 2; kk++)
        a[mi][kk] = *(const short8_t*)
            &lds[ab + (wm * 64 + mi * 16 + l16) * 64 + cs[kk]];
    #pragma unroll
    for (int ni = 0; ni < 4; ni++)
      #pragma unroll
      for (int kk = 0; kk < 2; kk++)
        b[ni][kk] = *(const short8_t*)
            &lds[ab + 8192 + (wn * 64 + ni * 16 + l16) * 64 + cs[kk]];
    __builtin_amdgcn_s_setprio(1);
    #pragma unroll
    for (int mi = 0; mi < 4; mi++)
      #pragma unroll
      for (int ni = 0; ni < 4; ni++)
        #pragma unroll
        for (int kk = 0; kk < 2; kk++)
          acc[mi][ni] = __builtin_amdgcn_mfma_f32_16x16x32_bf16(
              a[mi][kk], b[ni][kk], acc[mi][ni], 0, 0, 0);
    __builtin_amdgcn_s_setprio(0);
    if (t + 1 < NT) asm volatile("s_waitcnt vmcnt(0)" ::: "memory");
    BAR();                                  // tile t+1 resident; buf c reads done
  }

  #pragma unroll
  for (int mi = 0; mi < 4; mi++) {
    #pragma unroll
    for (int ni = 0; ni < 4; ni++) {
      #pragma unroll
      for (int j = 0; j < 4; j++) {
        const int r = m0 + wm * 64 + mi * 16 + kg * 4 + j;
        const int c = n0 + wn * 64 + ni * 16 + l16;
        const float v = acc[mi][ni][j];
        if (MODE == 15) {
          ((short*)Cp)[(size_t)r * N + c] = f2bf(v);
        } else if (MODE == 17) {
          ((short*)Cp)[(size_t)r * N + c] = f2bf(v + bias[c]);
        } else if (MODE == 6) {
          ((short*)Cp)[(size_t)r * N + c] = f2bf(fmaxf(v + bias[c], 0.f));
        } else if (MODE == 9) {
          ((float*)Cp)[(size_t)r * N + c] = v + bias[c];
        } else if (MODE == 8) {
          int kind = c >> 10, cc = c & 1023;
          int b2 = r >> 10, s = r & 1023, h = cc >> 6, hd = cc & 63;
          size_t off;
          if (kind < 2)
            off = (size_t)kind * MROWS * DD +
                  (((size_t)(b2 * HH + h) << 10) + s) * HDD + hd;
          else
            off = (size_t)2 * MROWS * DD +
                  (((size_t)(b2 * HH + h) * HDD + hd) << 10) + s;
          ((short*)Cp)[off] = f2bf(v);
        }
      }
    }
  }
}

__global__ __launch_bounds__(256, 2) void k_qkv(
    const short* __restrict__ A, const short* __restrict__ Bt,
    const float* __restrict__ bias, void* __restrict__ Cp,
    int M, int N, int K, int lda, int ldb) {
  extern __shared__ short lds[];
  gemm128db_body<8, 1>(lds, A, Bt, bias, Cp, M, N, K, lda, ldb);
}
__global__ __launch_bounds__(256, 2) void k_ffn1(
    const short* __restrict__ A, const short* __restrict__ Bt,
    const float* __restrict__ bias, void* __restrict__ Cp,
    int M, int N, int K, int lda, int ldb) {
  extern __shared__ short lds[];
  gemm128db_body<6, 1>(lds, A, Bt, bias, Cp, M, N, K, lda, ldb);
}
__global__ __launch_bounds__(256, 2) void k_logits(
    const short* __restrict__ A, const short* __restrict__ Bt,
    const float* __restrict__ bias, void* __restrict__ Cp,
    int M, int N, int K, int lda, int ldb) {
  extern __shared__ short lds[];
  gemm128db_body<9, 1>(lds, A, Bt, bias, Cp, M, N, K, lda, ldb);
}
__global__ __launch_bounds__(256, 2) void k_proj(
    const short* __restrict__ A, const short* __restrict__ Bt,
    const float* __restrict__ bias, void* __restrict__ Cp,
    int M, int N, int K, int lda, int ldb) {
  extern __shared__ short lds[];
  gemm128db_body<15, 0>(lds, A, Bt, bias, Cp, M, N, K, lda, ldb);
}
__global__ __launch_bounds__(256, 2) void k_ffn2(
    const short* __restrict__ A, const short* __restrict__ Bt,
    const float* __restrict__ bias, void* __restrict__ Cp,
    int M, int N, int K, int lda, int ldb) {
  extern __shared__ short lds[];
  gemm128db_body<17, 0>(lds, A, Bt, bias, Cp, M, N, K, lda, ldb);
}

// ======== flash attention v2: 8 waves, dbuf K/V, Q in regs, exp2 ========
#define RDSWZ(arr, r, cb) \
  (*(const short8_t*)&arr[((r) << 6) + ((((cb) ^ (((r) & 7) << 4))) >> 1)])
#define RDSWZ7(arr, r, cb) \
  (*(const short8_t*)&arr[((r) << 7) + ((((cb) ^ (((r) & 7) << 4))) >> 1)])

__global__ __launch_bounds__(512, 2) void k_attn(
    const short* __restrict__ Qg, const short* __restrict__ Kgl,
    const short* __restrict__ Vt, short* __restrict__ Og) {
  extern __shared__ short sm[];
  short* lP = sm + 32768;    // [128][128] swz
  const int tid = threadIdx.x;
  const int z = blockIdx.y;
  const int qb = (z < 32) ? blockIdx.x : 7 - blockIdx.x;  // CU load pairing
  const int q0 = qb << 7;
  const short* Qp = Qg + ((size_t)z << 16);   // [S][64]
  const short* Kp = Kgl + ((size_t)z << 16);  // [S][64]
  const short* Vp = Vt + ((size_t)z << 16);   // [64][S]
  const int bidx = z >> 4, h = z & 15;
  const int lane = tid & 63, w = tid >> 6;    // 8 waves
  const int l16 = lane & 15, kg = lane >> 4;
  const int sr = tid >> 3;                    // K/Q staging: 8 thr/row, 0..63
  const int scb = ((((tid & 7) << 4) ^ ((sr & 7) << 4)) >> 1);
  const int vr = tid >> 4;                    // V staging: 16 thr/row, 0..31
  const int vcb = ((((tid & 15) << 4) ^ ((vr & 7) << 4)) >> 1);
  const int ldst = (tid & ~63) << 3;          // wave-uniform elem base

  auto stageK = [&](int kt, int c) {
    const int k0 = kt << 7;
    short* dst = sm + c * 16384;
    #pragma unroll
    for (int i = 0; i < 2; i++)
      gload16(Kp + ((size_t)(k0 + i * 64 + sr) << 6) + scb,
              dst + i * 4096 + ldst);
  };
  auto stageV = [&](int kt, int c) {
    const int k0 = kt << 7;
    short* dst = sm + c * 16384 + 8192;
    #pragma unroll
    for (int i = 0; i < 2; i++)
      gload16(Vp + ((size_t)(i * 32 + vr) << 10) + k0 + vcb,
              dst + i * 4096 + ldst);
  };

  // ---- stage Q through Kbuf1, read to regs ----
  #pragma unroll
  for (int i = 0; i < 2; i++)
    gload16(Qp + ((size_t)(q0 + i * 64 + sr) << 6) + scb,
            sm + 16384 + i * 4096 + ldst);
  __syncthreads();                            // Q landed
  short8_t aq[2];
  #pragma unroll
  for (int kk = 0; kk < 2; kk++)
    aq[kk] = RDSWZ((sm + 16384), w * 16 + l16, kk * 64 + kg * 16);
  __syncthreads();                            // all waves' Q-reads complete

  f32x4 acc_o[4];
  float m_r[4], l_r[4];
  #pragma unroll
  for (int j = 0; j < 4; j++) {
    m_r[j] = -3e38f; l_r[j] = 0.f;
    #pragma unroll
    for (int n2 = 0; n2 < 4; n2++) acc_o[n2][j] = 0.f;
  }

  const float C = 0.125f * 1.44269504f;       // scale * log2(e)
  const int nkt = qb + 1;
  stageK(0, 0); stageV(0, 0);                 // prologue -> buf0

  for (int kt = 0; kt < nkt; kt++) {
    const int cur = kt & 1;
    if (kt + 1 < nkt) {
      stageK(kt + 1, cur ^ 1); stageV(kt + 1, cur ^ 1);
      asm volatile("s_waitcnt vmcnt(4)" ::: "memory");
    } else {
      asm volatile("s_waitcnt vmcnt(0)" ::: "memory");
    }
    BAR();                                    // tile kt data visible to all

    const short* lK = sm + cur * 16384;
    const short* lV = sm + cur * 16384 + 8192;
    const int k0 = kt << 7;

    // ---- S = Q K^T ----
    f32x4 s[8];
    #pragma unroll
    for (int nf = 0; nf < 8; nf++)
      #pragma unroll
      for (int j = 0; j < 4; j++) s[nf][j] = 0.f;
    #pragma unroll
    for (int kk = 0; kk < 2; kk++)
      #pragma unroll
      for (int nf = 0; nf < 8; nf++) {
        short8_t bk = RDSWZ(lK, nf * 16 + l16, kk * 64 + kg * 16);
        s[nf] = __builtin_amdgcn_mfma_f32_16x16x32_bf16(aq[kk], bk, s[nf], 0, 0, 0);
      }

    // ---- online softmax (exp2 domain) + P~ write ----
    const bool diag = (kt == qb);
    #pragma unroll
    for (int j = 0; j < 4; j++) {
      const int ql = w * 16 + kg * 4 + j;
      const int q = q0 + ql;
      float sv[8]; float tm = -3e38f;
      #pragma unroll
      for (int nf = 0; nf < 8; nf++) {
        const int kv = k0 + nf * 16 + l16;
        const float x = s[nf][j] * C;
        sv[nf] = (!diag || kv <= q) ? x : -3e38f;
        tm = fmaxf(tm, sv[nf]);
      }
      #pragma unroll
      for (int o = 1; o < 16; o <<= 1) tm = fmaxf(tm, __shfl_xor(tm, o));
      const float mn = fmaxf(m_r[j], tm);
      const float scale = exp2f(m_r[j] - mn);
      float ts = 0.f;
      #pragma unroll
      for (int nf = 0; nf < 8; nf++) {
        const float e = exp2f(sv[nf] - mn);
        ts += e;
        lP[(ql << 7) + ((nf * 16 + l16) ^ ((ql & 7) << 3))] = f2bf(e);
      }
      #pragma unroll
      for (int o = 1; o < 16; o <<= 1) ts += __shfl_xor(ts, o);
      l_r[j] = l_r[j] * scale + ts;
      m_r[j] = mn;
      #pragma unroll
      for (int n2 = 0; n2 < 4; n2++) acc_o[n2][j] *= scale;
    }

    // ---- O += P~ V  (P wave-private: rows w*16..w*16+15) ----
    #pragma unroll
    for (int kc = 0; kc < 4; kc++) {
      const int pr = w * 16 + l16;
      short8_t pa = *(const short8_t*)
          &lP[(pr << 7) + ((kc * 32 + kg * 8) ^ ((pr & 7) << 3))];
      #pragma unroll
      for (int n2 = 0; n2 < 4; n2++) {
        short8_t vb = RDSWZ7(lV, n2 * 16 + l16, kc * 64 + kg * 16);
        acc_o[n2] = __builtin_amdgcn_mfma_f32_16x16x32_bf16(pa, vb, acc_o[n2], 0, 0, 0);
      }
    }
    BAR();                 // all waves done with buf cur before its overwrite
  }

  // ---- normalize + write O[b, s, h*64 + hd] ----
  #pragma unroll
  for (int j = 0; j < 4; j++) {
    const int q = q0 + w * 16 + kg * 4 + j;
    const float inv = 1.f / l_r[j];
    #pragma unroll
    for (int n2 = 0; n2 < 4; n2++) {
      const int col = h * HDD + n2 * 16 + l16;
      Og[(((size_t)bidx << 10) + q) * DD + col] = f2bf(acc_o[n2][j] * inv);
    }
  }
}

// ------- LayerNorm (D=1024), src fp32 or bf16, optional residual -------
template<int SRCB16, int ADD_RES, int WRITE_F32>
__global__ __launch_bounds__(256) void k_ln(
    const void* __restrict__ src, const float* __restrict__ res,
    const float* __restrict__ g, const float* __restrict__ b,
    float* __restrict__ of, short* __restrict__ ob) {
  const int row = blockIdx.x;
  const int tid = threadIdx.x;
  float4 v;
  if (SRCB16) {
    short4 s = ((const short4*)src)[((size_t)row << 8) + tid];
    v.x = bf2f(s.x); v.y = bf2f(s.y); v.z = bf2f(s.z); v.w = bf2f(s.w);
  } else {
    v = ((const float4*)src)[((size_t)row << 8) + tid];
  }
  float s1 = v.x + v.y + v.z + v.w;
  float s2 = v.x * v.x + v.y * v.y + v.z * v.z + v.w * v.w;
  #pragma unroll
  for (int o = 32; o; o >>= 1) { s1 += __shfl_xor(s1, o); s2 += __shfl_xor(s2, o); }
  __shared__ float sh1[4], sh2[4];
  if ((tid & 63) == 0) { sh1[tid >> 6] = s1; sh2[tid >> 6] = s2; }
  __syncthreads();
  s1 = sh1[0] + sh1[1] + sh1[2] + sh1[3];
  s2 = sh2[0] + sh2[1] + sh2[2] + sh2[3];
  const float mean = s1 * (1.f / 1024.f);
  const float var  = s2 * (1.f / 1024.f) - mean * mean;
  const float rs = rsqrtf(var + 1e-5f);
  float4 gg = ((const float4*)g)[tid];
  float4 bb = ((const float4*)b)[tid];
  float4 o4;
  o4.x = (v.x - mean) * rs * gg.x + bb.x;
  o4.y = (v.y - mean) * rs * gg.y + bb.y;
  o4.z = (v.z - mean) * rs * gg.z + bb.z;
  o4.w = (v.w - mean) * rs * gg.w + bb.w;
  if (ADD_RES) {
    float4 rr = ((const float4*)(res + ((size_t)row << 10)))[tid];
    o4.x += rr.x; o4.y += rr.y; o4.z += rr.z; o4.w += rr.w;
  }
  if (WRITE_F32) ((float4*)(of + ((size_t)row << 10)))[tid] = o4;
  short4 s4; s4.x = f2bf(o4.x); s4.y = f2bf(o4.y);
  s4.z = f2bf(o4.z); s4.w = f2bf(o4.w);
  ((short4*)ob)[((size_t)row << 8) + tid] = s4;
}

extern "C" void kernel_launch(void* const* d_in, const int* in_sizes, int n_in,
                              void* d_out, int out_size, void* d_ws, size_t ws_size,
                              hipStream_t stream) {
  (void)in_sizes; (void)n_in; (void)out_size; (void)ws_size;
  const int*   tokens  = (const int*)d_in[0];
  const float* tok_emb = (const float*)d_in[1];
  const float* pos_emb = (const float*)d_in[2];
  const float* Wq = (const float*)d_in[3];
  const float* Wk = (const float*)d_in[4];
  const float* Wv = (const float*)d_in[5];
  const float* Wp = (const float*)d_in[6];
  const float* ln1s = (const float*)d_in[7];
  const float* ln1b = (const float*)d_in[8];
  const float* W1 = (const float*)d_in[9];
  const float* b1 = (const float*)d_in[10];
  const float* W2 = (const float*)d_in[11];
  const float* b2 = (const float*)d_in[12];
  const float* ln2s = (const float*)d_in[13];
  const float* ln2b = (const float*)d_in[14];
  const float* lnfs = (const float*)d_in[15];
  const float* lnfb = (const float*)d_in[16];
  const float* Wh = (const float*)d_in[17];
  const float* bh = (const float*)d_in[18];
  float* out = (float*)d_out;

  hipFuncSetAttribute((const void*)k_qkv,
      hipFuncAttributeMaxDynamicSharedMemorySize, 65536);
  hipFuncSetAttribute((const void*)k_ffn1,
      hipFuncAttributeMaxDynamicSharedMemorySize, 65536);
  hipFuncSetAttribute((const void*)k_logits,
      hipFuncAttributeMaxDynamicSharedMemorySize, 65536);
  hipFuncSetAttribute((const void*)k_proj,
      hipFuncAttributeMaxDynamicSharedMemorySize, 65536);
  hipFuncSetAttribute((const void*)k_ffn2,
      hipFuncAttributeMaxDynamicSharedMemorySize, 65536);
  hipFuncSetAttribute((const void*)k_attn,
      hipFuncAttributeMaxDynamicSharedMemorySize, 98304);

  char* p = (char*)d_ws;
  auto alloc = [&](size_t elems, size_t esz) -> char* {
    char* r = p; p += (elems * esz + 255) & ~(size_t)255; return r;
  };
  short* WqkvT = (short*)alloc((size_t)LNUM * 3 * DD * DD, 2);  // [L][3][D][D]
  short* WpT = (short*)alloc((size_t)LNUM * DD * DD, 2);
  short* W1T = (short*)alloc((size_t)LNUM * DD * FF, 2);
  short* W2T = (short*)alloc((size_t)LNUM * DD * FF, 2);
  short* WhT = (short*)alloc((size_t)DD * VV, 2);
  float* xf   = (float*)alloc((size_t)MROWS * DD, 4);   // fp32 residual stream
  short* ffb  = (short*)alloc((size_t)MROWS * DD, 2);   // bf16 GEMM-out for LN
  short* xb   = (short*)alloc((size_t)MROWS * DD, 2);
  short* ab   = (short*)alloc((size_t)MROWS * DD, 2);
  short* qkvb = (short*)alloc((size_t)3 * MROWS * DD, 2); // q | k | v^T contiguous
  short* obuf = (short*)alloc((size_t)MROWS * DD, 2);
  short* hb   = (short*)alloc((size_t)MROWS * FF, 2);
  short* xfb  = (short*)alloc((size_t)MROWS * DD, 2);
  short* qb   = qkvb;
  short* kb   = qkvb + (size_t)MROWS * DD;
  short* vtb  = qkvb + (size_t)2 * MROWS * DD;

  dim3 blk(256);
  const long long DD2 = (long long)DD * DD;
  const long long DF  = (long long)DD * FF;
  // vectorized weight convert+transpose
  k_tcvt4q<<<dim3(16, 16, 3 * LNUM), blk, 0, stream>>>(Wq, Wk, Wv, WqkvT);
  k_tcvt4<<<dim3(16, 16, LNUM), blk, 0, stream>>>(Wp, WpT, DD, DD, DD2, DD2);
  k_tcvt4<<<dim3(64, 16, LNUM), blk, 0, stream>>>(W1, W1T, DD, FF, DF, DF);
  k_tcvt4<<<dim3(16, 64, LNUM), blk, 0, stream>>>(W2, W2T, FF, DD, DF, DF);
  k_tcvt4<<<dim3(500, 16, 1),  blk, 0, stream>>>(Wh, WhT, DD, VV, 0, 0);

  k_embed<<<(MROWS * DD / 4) / 256, blk, 0, stream>>>(tokens, tok_emb, pos_emb, xf, xb);

  for (int l = 0; l < LNUM; l++) {
    const short* wqkv = WqkvT + (size_t)l * 3 * DD * DD;
    const short* wp = WpT + (size_t)l * DD * DD;
    const short* w1 = W1T + (size_t)l * DD * FF;
    const short* w2 = W2T + (size_t)l * DD * FF;

    // fused QKV projection: [4096 x 3072 x 1024]  (dbuf 128^2, XCD swz)
    k_qkv<<<dim3(24, 32), blk, 65536, stream>>>(xb, wqkv, nullptr, qkvb,
        MROWS, 3 * DD, DD, DD, DD);
    // flash attention v2 -> obuf [B,S,D]
    k_attn<<<dim3(8, BB * HH), 512, 98304, stream>>>(qb, kb, vtb, obuf);
    // proj: [4096 x 1024 x 1024] -> bf16 ffb
    k_proj<<<dim3(8, 32), blk, 65536, stream>>>(obuf, wp, nullptr, ffb,
        MROWS, DD, DD, DD, DD);
    k_ln<1, 1, 0><<<MROWS, blk, 0, stream>>>(ffb, xf, ln1s + (size_t)l * DD,
        ln1b + (size_t)l * DD, nullptr, ab);
    // ffn1: [4096 x 4096 x 1024]  (dbuf 128^2, XCD swz)
    k_ffn1<<<dim3(32, 32), blk, 65536, stream>>>(ab, w1, b1 + (size_t)l * FF, hb,
        MROWS, FF, DD, DD, DD);
    // ffn2: [4096 x 1024 x 4096] -> bf16 ffb
    k_ffn2<<<dim3(8, 32), blk, 65536, stream>>>(hb, w2, b2 + (size_t)l * DD, ffb,
        MROWS, DD, FF, FF, FF);
    k_ln<1, 1, 1><<<MROWS, blk, 0, stream>>>(ffb, xf, ln2s + (size_t)l * DD,
        ln2b + (size_t)l * DD, xf, xb);
  }

  k_ln<0, 0, 0><<<MROWS, blk, 0, stream>>>(xf, nullptr, lnfs, lnfb, nullptr, xfb);
  // logits = lnf(x) @ Wh + bh : [4096 x 32000 x 1024]  (dbuf 128^2, XCD swz)
  k_logits<<<dim3(VV / 128, 32), blk, 65536, stream>>>(xfb, WhT, bh, out,
      MROWS, VV, DD, DD, DD);
}

// Round 14
// 1983.573 us; speedup vs baseline: 1.0851x; 1.0851x over previous
//
#include <hip/hip_runtime.h>

#define DEV __device__ __forceinline__

typedef __attribute__((ext_vector_type(4))) float f32x4;
typedef __attribute__((ext_vector_type(8))) short short8_t;

constexpr int LNUM = 6;
constexpr int BB = 4;
constexpr int SS = 1024;
constexpr int DD = 1024;
constexpr int HH = 16;
constexpr int HDD = 64;
constexpr int FF = 4096;
constexpr int VV = 32000;
constexpr int MROWS = BB * SS;   // 4096

DEV short f2bf(float f) {
  union { float f; unsigned u; } x; x.f = f;
  unsigned r = x.u + 0x7fffu + ((x.u >> 16) & 1u);   // RNE
  return (short)(r >> 16);
}

DEV float bf2f(short s) {
  union { unsigned u; float f; } x;
  x.u = ((unsigned)(unsigned short)s) << 16;
  return x.f;
}

#define BAR() do { __builtin_amdgcn_sched_barrier(0); \
  __builtin_amdgcn_s_barrier(); \
  __builtin_amdgcn_sched_barrier(0); } while (0)

// ---------------- embedding: x = tok_emb[tok] + pos_emb ----------------
__global__ __launch_bounds__(256) void k_embed(
    const int* __restrict__ tok, const float* __restrict__ te,
    const float* __restrict__ pe, float* __restrict__ xf,
    short* __restrict__ xb) {
  int i = blockIdx.x * 256 + threadIdx.x;            // over MROWS*DD/4
  int bs = i >> 8, d4 = i & 255;
  int t = tok[bs];
  float4 a = ((const float4*)(te + (size_t)t * DD))[d4];
  float4 b = ((const float4*)(pe + (size_t)(bs & (SS - 1)) * DD))[d4];
  float4 r; r.x = a.x + b.x; r.y = a.y + b.y; r.z = a.z + b.z; r.w = a.w + b.w;
  ((float4*)xf)[i] = r;
  short4 o; o.x = f2bf(r.x); o.y = f2bf(r.y); o.z = f2bf(r.z); o.w = f2bf(r.w);
  ((short4*)xb)[i] = o;
}

// ---- vectorized transpose+cvt: W[K,N] -> Wt[N,K] bf16, 64x64 tiles ----
__global__ __launch_bounds__(256) void k_tcvt4(
    const float* __restrict__ in, short* __restrict__ out, int K, int N,
    long long istride, long long ostride) {
  __shared__ float tile[64][65];
  const float* ip = in + (size_t)blockIdx.z * istride;
  short* op = out + (size_t)blockIdx.z * ostride;
  const int bn = blockIdx.x * 64, bk = blockIdx.y * 64;
  const int tc = threadIdx.x & 15, tr = threadIdx.x >> 4;  // 16 col4 x 16 rows
  #pragma unroll
  for (int i = 0; i < 4; i++) {
    const int r = tr + 16 * i;
    float4 v = *(const float4*)&ip[(size_t)(bk + r) * N + bn + tc * 4];
    tile[r][tc * 4 + 0] = v.x; tile[r][tc * 4 + 1] = v.y;
    tile[r][tc * 4 + 2] = v.z; tile[r][tc * 4 + 3] = v.w;
  }
  __syncthreads();
  #pragma unroll
  for (int i = 0; i < 4; i++) {
    const int wr = tr + 16 * i;           // output row (n)
    short4 s;
    s.x = f2bf(tile[tc * 4 + 0][wr]);
    s.y = f2bf(tile[tc * 4 + 1][wr]);
    s.z = f2bf(tile[tc * 4 + 2][wr]);
    s.w = f2bf(tile[tc * 4 + 3][wr]);
    *(short4*)&op[(size_t)(bn + wr) * K + bk + tc * 4] = s;
  }
}

// ---- same, 3-source merged q/k/v: z = l*3 + which, dst [L][3][D][D] ----
__global__ __launch_bounds__(256) void k_tcvt4q(
    const float* __restrict__ Wq, const float* __restrict__ Wk,
    const float* __restrict__ Wv, short* __restrict__ out) {
  __shared__ float tile[64][65];
  const int z = blockIdx.z, l = z / 3, which = z - l * 3;
  const float* ip = (which == 0 ? Wq : which == 1 ? Wk : Wv)
                    + (size_t)l * DD * DD;
  short* op = out + (size_t)z * DD * DD;
  const int bn = blockIdx.x * 64, bk = blockIdx.y * 64;
  const int tc = threadIdx.x & 15, tr = threadIdx.x >> 4;
  #pragma unroll
  for (int i = 0; i < 4; i++) {
    const int r = tr + 16 * i;
    float4 v = *(const float4*)&ip[(size_t)(bk + r) * DD + bn + tc * 4];
    tile[r][tc * 4 + 0] = v.x; tile[r][tc * 4 + 1] = v.y;
    tile[r][tc * 4 + 2] = v.z; tile[r][tc * 4 + 3] = v.w;
  }
  __syncthreads();
  #pragma unroll
  for (int i = 0; i < 4; i++) {
    const int wr = tr + 16 * i;
    short4 s;
    s.x = f2bf(tile[tc * 4 + 0][wr]);
    s.y = f2bf(tile[tc * 4 + 1][wr]);
    s.z = f2bf(tile[tc * 4 + 2][wr]);
    s.w = f2bf(tile[tc * 4 + 3][wr]);
    *(short4*)&op[(size_t)(bn + wr) * DD + bk + tc * 4] = s;
  }
}

DEV void gload16(const short* g, short* l) {
  __builtin_amdgcn_global_load_lds(
      (const __attribute__((address_space(1))) void*)g,
      (__attribute__((address_space(3))) void*)l, 16, 0, 0);
}

// ============ 256x256 8-phase bf16 GEMM body, BK=64 (logits only) ============
// Round-12-exact. vmcnt is PER-WAVE; window issues 8 vm-ops/wave; vmcnt(8)
// drains tile t+1 and leaves t+2's 8 in flight. MODE 9: fp32+bias with
// interleaved quadrant stores. N-major XCD chunks (bx=lid>>4, by=lid&15).
template<int MODE>
DEV void gemm256_body(short* lds,
    const short* __restrict__ A, const short* __restrict__ Bt,
    const float* __restrict__ bias, void* __restrict__ Cp,
    int M, int N, int K, int lda, int ldb) {
  const int tid = threadIdx.x;
  const int nbx = gridDim.x;
  const int nwg = nbx << 4;
  const int hid = blockIdx.y * nbx + blockIdx.x;
  const int cpx = nwg >> 3;
  const int lid = (hid & 7) * cpx + (hid >> 3);
  const int bx = lid >> 4, by = lid & 15;
  const int n0 = bx * 256, m0 = by * 256;

  const int lane = tid & 63;
  const int wid = tid >> 6;
  const int wm = wid >> 2, wn = wid & 3;
  const int l16 = lane & 15, kg = lane >> 4;
  const int xorv = (l16 & 7) << 4;
  const int cs[2] = { ((kg << 4) ^ xorv) >> 1,
                      ((64 | (kg << 4)) ^ xorv) >> 1 };
  const int rr = tid >> 3;
  const int sce = ((((tid & 7) << 4) ^ ((rr & 7) << 4)) >> 1);
  const int ldst = (tid & ~63) * 8;

  const int NT = K >> 6;

  auto stageA = [&](int t2, int c2) {
    const int k0 = t2 << 6;
    const int base = c2 * 32768;
    #pragma unroll
    for (int h = 0; h < 2; h++)
      #pragma unroll
      for (int li = 0; li < 2; li++)
        gload16(A + (size_t)(m0 + h * 128 + li * 64 + rr) * lda + k0 + sce,
                &lds[base + h * 8192 + li * 4096 + ldst]);
  };
  auto stageB = [&](int t2, int c2) {
    const int k0 = t2 << 6;
    const int base = c2 * 32768 + 16384;
    #pragma unroll
    for (int h = 0; h < 2; h++)
      #pragma unroll
      for (int li = 0; li < 2; li++)
        gload16(Bt + (size_t)(n0 + h * 128 + li * 64 + rr) * ldb + k0 + sce,
                &lds[base + h * 8192 + li * 4096 + ldst]);
  };

  f32x4 acc[8][4];
  #pragma unroll
  for (int mi = 0; mi < 8; mi++)
    #pragma unroll
    for (int ni = 0; ni < 4; ni++)
      #pragma unroll
      for (int j = 0; j < 4; j++) acc[mi][ni][j] = 0.f;

  auto storeQ = [&](int mlo, int nlo) {
    #pragma unroll
    for (int mi = 0; mi < 4; mi++)
      #pragma unroll
      for (int ni = 0; ni < 2; ni++)
        #pragma unroll
        for (int j = 0; j < 4; j++) {
          const int r = m0 + wm * 128 + (mlo + mi) * 16 + kg * 4 + j;
          const int c = n0 + wn * 64 + (nlo + ni) * 16 + l16;
          ((float*)Cp)[(size_t)r * N + c] = acc[mlo + mi][nlo + ni][j] + bias[c];
        }
  };

  stageA(0, 0); stageB(0, 0);
  stageA(1, 1); stageB(1, 1);
  asm volatile("s_waitcnt vmcnt(8)" ::: "memory");
  BAR();

  for (int t = 0; t < NT; t++) {
    const int c = t & 1;
    const int ao = c * 32768 + wm * 8192;
    const int bo = c * 32768 + 16384 + (wn >> 1) * 8192 + (wn & 1) * 4096;
    short8_t a[4][2], b0[2][2], b1[2][2];

    // ---- P0 ----
    #pragma unroll
    for (int mi = 0; mi < 4; mi++)
      #pragma unroll
      for (int kk = 0; kk < 2; kk++)
        a[mi][kk] = *(const short8_t*)&lds[ao + (mi * 16 + l16) * 64 + cs[kk]];
    #pragma unroll
    for (int ni = 0; ni < 2; ni++)
      #pragma unroll
      for (int kk = 0; kk < 2; kk++)
        b0[ni][kk] = *(const short8_t*)&lds[bo + (ni * 16 + l16) * 64 + cs[kk]];
    BAR();
    __builtin_amdgcn_s_setprio(1);
    #pragma unroll
    for (int mi = 0; mi < 4; mi++)
      #pragma unroll
      for (int ni = 0; ni < 2; ni++)
        #pragma unroll
        for (int kk = 0; kk < 2; kk++)
          acc[mi][ni] = __builtin_amdgcn_mfma_f32_16x16x32_bf16(
              a[mi][kk], b0[ni][kk], acc[mi][ni], 0, 0, 0);
    __builtin_amdgcn_s_setprio(0);
    if (MODE == 9 && t == NT - 1) storeQ(0, 0);
    BAR();

    // ---- P1 ----
    #pragma unroll
    for (int ni = 0; ni < 2; ni++)
      #pragma unroll
      for (int kk = 0; kk < 2; kk++)
        b1[ni][kk] = *(const short8_t*)&lds[bo + ((ni + 2) * 16 + l16) * 64 + cs[kk]];
    BAR();
    __builtin_amdgcn_s_setprio(1);
    #pragma unroll
    for (int mi = 0; mi < 4; mi++)
      #pragma unroll
      for (int ni = 0; ni < 2; ni++)
        #pragma unroll
        for (int kk = 0; kk < 2; kk++)
          acc[mi][ni + 2] = __builtin_amdgcn_mfma_f32_16x16x32_bf16(
              a[mi][kk], b1[ni][kk], acc[mi][ni + 2], 0, 0, 0);
    __builtin_amdgcn_s_setprio(0);
    if (MODE == 9 && t == NT - 1) storeQ(0, 2);
    BAR();

    // ---- P2 ----
    #pragma unroll
    for (int mi = 0; mi < 4; mi++)
      #pragma unroll
      for (int kk = 0; kk < 2; kk++)
        a[mi][kk] = *(const short8_t*)&lds[ao + ((mi + 4) * 16 + l16) * 64 + cs[kk]];
    if (t + 2 < NT) stageB(t + 2, c);
    BAR();
    __builtin_amdgcn_s_setprio(1);
    #pragma unroll
    for (int mi = 0; mi < 4; mi++)
      #pragma unroll
      for (int ni = 0; ni < 2; ni++)
        #pragma unroll
        for (int kk = 0; kk < 2; kk++)
          acc[mi + 4][ni + 2] = __builtin_amdgcn_mfma_f32_16x16x32_bf16(
              a[mi][kk], b1[ni][kk], acc[mi + 4][ni + 2], 0, 0, 0);
    __builtin_amdgcn_s_setprio(0);
    if (MODE == 9 && t == NT - 1) storeQ(4, 2);
    BAR();

    // ---- P3 ----
    if (t + 2 < NT) stageA(t + 2, c);
    BAR();
    __builtin_amdgcn_s_setprio(1);
    #pragma unroll
    for (int mi = 0; mi < 4; mi++)
      #pragma unroll
      for (int ni = 0; ni < 2; ni++)
        #pragma unroll
        for (int kk = 0; kk < 2; kk++)
          acc[mi + 4][ni] = __builtin_amdgcn_mfma_f32_16x16x32_bf16(
              a[mi][kk], b0[ni][kk], acc[mi + 4][ni], 0, 0, 0);
    __builtin_amdgcn_s_setprio(0);
    if (t + 2 < NT) asm volatile("s_waitcnt vmcnt(8)" ::: "memory");
    else            asm volatile("s_waitcnt vmcnt(0)" ::: "memory");
    BAR();
  }

  if (MODE == 9) storeQ(4, 0);
}

__global__ __launch_bounds__(512, 2) void k_logits(
    const short* __restrict__ A, const short* __restrict__ Bt,
    const float* __restrict__ bias, void* __restrict__ Cp,
    int M, int N, int K, int lda, int ldb) {
  extern __shared__ short lds[];
  gemm256_body<9>(lds, A, Bt, bias, Cp, M, N, K, lda, ldb);
}

// ====== 128x128 dbuf-counted bf16 GEMM (BK=64, 2 blocks/CU) ======
// Round-12's winner. stage(t+1) into the OTHER buffer at window top;
// 16 ds_reads + 32 MFMA of tile t; vmcnt(0)+BAR gates tile t+1.
// NO explicit XCD swizzle: with grid (X,32) the natural i%8 round-robin
// pins bx columns per XCD -> B-panels L2-resident (round-13 lesson: the
// explicit B-major swizzle REGRESSED; default order is near-optimal here).
// MODEs: 6 relu+bias->bf16; 8 QKV scatter; 15 bf16; 17 bf16+bias.
template<int MODE>
DEV void gemm128db_body(short* lds,
    const short* __restrict__ A, const short* __restrict__ Bt,
    const float* __restrict__ bias, void* __restrict__ Cp,
    int M, int N, int K, int lda, int ldb) {
  const int tid = threadIdx.x;
  const int n0 = blockIdx.x * 128, m0 = blockIdx.y * 128;
  const int lane = tid & 63;
  const int wid = tid >> 6;                 // 4 waves: 2M x 2N
  const int wm = wid >> 1, wn = wid & 1;
  const int l16 = lane & 15, kg = lane >> 4;
  const int xorv = (l16 & 7) << 4;
  const int cs[2] = { ((kg << 4) ^ xorv) >> 1,
                      ((64 | (kg << 4)) ^ xorv) >> 1 };
  const int rr = tid >> 3;                  // 0..31 (8 thr/row)
  const int sce = ((((tid & 7) << 4) ^ ((rr & 7) << 4)) >> 1);
  const int ldst = (tid & ~63) * 8;         // wave-uniform elem base

  const int NT = K >> 6;

  auto stage = [&](int t2, int c2) {
    const int k0 = t2 << 6;
    const int base = c2 * 16384;            // buf = 16384 shorts (A 8K | B 8K)
    #pragma unroll
    for (int i = 0; i < 4; i++)
      gload16(A + (size_t)(m0 + i * 32 + rr) * lda + k0 + sce,
              &lds[base + i * 2048 + ldst]);
    #pragma unroll
    for (int i = 0; i < 4; i++)
      gload16(Bt + (size_t)(n0 + i * 32 + rr) * ldb + k0 + sce,
              &lds[base + 8192 + i * 2048 + ldst]);
  };

  f32x4 acc[4][4];
  #pragma unroll
  for (int a = 0; a < 4; a++)
    #pragma unroll
    for (int b = 0; b < 4; b++)
      #pragma unroll
      for (int j = 0; j < 4; j++) acc[a][b][j] = 0.f;

  stage(0, 0);
  asm volatile("s_waitcnt vmcnt(0)" ::: "memory");
  BAR();

  for (int t = 0; t < NT; t++) {
    const int c = t & 1;
    if (t + 1 < NT) stage(t + 1, c ^ 1);    // other buffer: no in-window hazard
    const int ab = c * 16384;
    short8_t a[4][2], b[4][2];
    #pragma unroll
    for (int mi = 0; mi < 4; mi++)
      #pragma unroll
      for (int kk = 0; kk < 2; kk++)
        a[mi][kk] = *(const short8_t*)
            &lds[ab + (wm * 64 + mi * 16 + l16) * 64 + cs[kk]];
    #pragma unroll
    for (int ni = 0; ni < 4; ni++)
      #pragma unroll
      for (int kk = 0; kk < 2; kk++)
        b[ni][kk] = *(const short8_t*)
            &lds[ab + 8192 + (wn * 64 + ni * 16 + l16) * 64 + cs[kk]];
    __builtin_amdgcn_s_setprio(1);
    #pragma unroll
    for (int mi = 0; mi < 4; mi++)
      #pragma unroll
      for (int ni = 0; ni < 4; ni++)
        #pragma unroll
        for (int kk = 0; kk < 2; kk++)
          acc[mi][ni] = __builtin_amdgcn_mfma_f32_16x16x32_bf16(
              a[mi][kk], b[ni][kk], acc[mi][ni], 0, 0, 0);
    __builtin_amdgcn_s_setprio(0);
    if (t + 1 < NT) asm volatile("s_waitcnt vmcnt(0)" ::: "memory");
    BAR();                                  // tile t+1 resident; buf c reads done
  }

  #pragma unroll
  for (int mi = 0; mi < 4; mi++) {
    #pragma unroll
    for (int ni = 0; ni < 4; ni++) {
      #pragma unroll
      for (int j = 0; j < 4; j++) {
        const int r = m0 + wm * 64 + mi * 16 + kg * 4 + j;
        const int c = n0 + wn * 64 + ni * 16 + l16;
        const float v = acc[mi][ni][j];
        if (MODE == 15) {
          ((short*)Cp)[(size_t)r * N + c] = f2bf(v);
        } else if (MODE == 17) {
          ((short*)Cp)[(size_t)r * N + c] = f2bf(v + bias[c]);
        } else if (MODE == 6) {
          ((short*)Cp)[(size_t)r * N + c] = f2bf(fmaxf(v + bias[c], 0.f));
        } else if (MODE == 8) {
          int kind = c >> 10, cc = c & 1023;
          int b2 = r >> 10, s = r & 1023, h = cc >> 6, hd = cc & 63;
          size_t off;
          if (kind < 2)
            off = (size_t)kind * MROWS * DD +
                  (((size_t)(b2 * HH + h) << 10) + s) * HDD + hd;
          else
            off = (size_t)2 * MROWS * DD +
                  (((size_t)(b2 * HH + h) * HDD + hd) << 10) + s;
          ((short*)Cp)[off] = f2bf(v);
        }
      }
    }
  }
}

__global__ __launch_bounds__(256, 2) void k_qkv(
    const short* __restrict__ A, const short* __restrict__ Bt,
    const float* __restrict__ bias, void* __restrict__ Cp,
    int M, int N, int K, int lda, int ldb) {
  extern __shared__ short lds[];
  gemm128db_body<8>(lds, A, Bt, bias, Cp, M, N, K, lda, ldb);
}
__global__ __launch_bounds__(256, 2) void k_ffn1(
    const short* __restrict__ A, const short* __restrict__ Bt,
    const float* __restrict__ bias, void* __restrict__ Cp,
    int M, int N, int K, int lda, int ldb) {
  extern __shared__ short lds[];
  gemm128db_body<6>(lds, A, Bt, bias, Cp, M, N, K, lda, ldb);
}
__global__ __launch_bounds__(256, 2) void k_proj(
    const short* __restrict__ A, const short* __restrict__ Bt,
    const float* __restrict__ bias, void* __restrict__ Cp,
    int M, int N, int K, int lda, int ldb) {
  extern __shared__ short lds[];
  gemm128db_body<15>(lds, A, Bt, bias, Cp, M, N, K, lda, ldb);
}
__global__ __launch_bounds__(256, 2) void k_ffn2(
    const short* __restrict__ A, const short* __restrict__ Bt,
    const float* __restrict__ bias, void* __restrict__ Cp,
    int M, int N, int K, int lda, int ldb) {
  extern __shared__ short lds[];
  gemm128db_body<17>(lds, A, Bt, bias, Cp, M, N, K, lda, ldb);
}

// ======== flash attention v2: 8 waves, dbuf K/V, Q in regs, exp2 ========
#define RDSWZ(arr, r, cb) \
  (*(const short8_t*)&arr[((r) << 6) + ((((cb) ^ (((r) & 7) << 4))) >> 1)])
#define RDSWZ7(arr, r, cb) \
  (*(const short8_t*)&arr[((r) << 7) + ((((cb) ^ (((r) & 7) << 4))) >> 1)])

__global__ __launch_bounds__(512, 2) void k_attn(
    const short* __restrict__ Qg, const short* __restrict__ Kgl,
    const short* __restrict__ Vt, short* __restrict__ Og) {
  extern __shared__ short sm[];
  short* lP = sm + 32768;    // [128][128] swz
  const int tid = threadIdx.x;
  const int z = blockIdx.y;
  const int qb = (z < 32) ? blockIdx.x : 7 - blockIdx.x;  // CU load pairing
  const int q0 = qb << 7;
  const short* Qp = Qg + ((size_t)z << 16);   // [S][64]
  const short* Kp = Kgl + ((size_t)z << 16);  // [S][64]
  const short* Vp = Vt + ((size_t)z << 16);   // [64][S]
  const int bidx = z >> 4, h = z & 15;
  const int lane = tid & 63, w = tid >> 6;    // 8 waves
  const int l16 = lane & 15, kg = lane >> 4;
  const int sr = tid >> 3;                    // K/Q staging: 8 thr/row, 0..63
  const int scb = ((((tid & 7) << 4) ^ ((sr & 7) << 4)) >> 1);
  const int vr = tid >> 4;                    // V staging: 16 thr/row, 0..31
  const int vcb = ((((tid & 15) << 4) ^ ((vr & 7) << 4)) >> 1);
  const int ldst = (tid & ~63) << 3;          // wave-uniform elem base

  auto stageK = [&](int kt, int c) {
    const int k0 = kt << 7;
    short* dst = sm + c * 16384;
    #pragma unroll
    for (int i = 0; i < 2; i++)
      gload16(Kp + ((size_t)(k0 + i * 64 + sr) << 6) + scb,
              dst + i * 4096 + ldst);
  };
  auto stageV = [&](int kt, int c) {
    const int k0 = kt << 7;
    short* dst = sm + c * 16384 + 8192;
    #pragma unroll
    for (int i = 0; i < 2; i++)
      gload16(Vp + ((size_t)(i * 32 + vr) << 10) + k0 + vcb,
              dst + i * 4096 + ldst);
  };

  // ---- stage Q through Kbuf1, read to regs ----
  #pragma unroll
  for (int i = 0; i < 2; i++)
    gload16(Qp + ((size_t)(q0 + i * 64 + sr) << 6) + scb,
            sm + 16384 + i * 4096 + ldst);
  __syncthreads();                            // Q landed
  short8_t aq[2];
  #pragma unroll
  for (int kk = 0; kk < 2; kk++)
    aq[kk] = RDSWZ((sm + 16384), w * 16 + l16, kk * 64 + kg * 16);
  __syncthreads();                            // all waves' Q-reads complete

  f32x4 acc_o[4];
  float m_r[4], l_r[4];
  #pragma unroll
  for (int j = 0; j < 4; j++) {
    m_r[j] = -3e38f; l_r[j] = 0.f;
    #pragma unroll
    for (int n2 = 0; n2 < 4; n2++) acc_o[n2][j] = 0.f;
  }

  const float C = 0.125f * 1.44269504f;       // scale * log2(e)
  const int nkt = qb + 1;
  stageK(0, 0); stageV(0, 0);                 // prologue -> buf0

  for (int kt = 0; kt < nkt; kt++) {
    const int cur = kt & 1;
    if (kt + 1 < nkt) {
      stageK(kt + 1, cur ^ 1); stageV(kt + 1, cur ^ 1);
      asm volatile("s_waitcnt vmcnt(4)" ::: "memory");
    } else {
      asm volatile("s_waitcnt vmcnt(0)" ::: "memory");
    }
    BAR();                                    // tile kt data visible to all

    const short* lK = sm + cur * 16384;
    const short* lV = sm + cur * 16384 + 8192;
    const int k0 = kt << 7;

    // ---- S = Q K^T ----
    f32x4 s[8];
    #pragma unroll
    for (int nf = 0; nf < 8; nf++)
      #pragma unroll
      for (int j = 0; j < 4; j++) s[nf][j] = 0.f;
    #pragma unroll
    for (int kk = 0; kk < 2; kk++)
      #pragma unroll
      for (int nf = 0; nf < 8; nf++) {
        short8_t bk = RDSWZ(lK, nf * 16 + l16, kk * 64 + kg * 16);
        s[nf] = __builtin_amdgcn_mfma_f32_16x16x32_bf16(aq[kk], bk, s[nf], 0, 0, 0);
      }

    // ---- online softmax (exp2 domain) + P~ write ----
    const bool diag = (kt == qb);
    #pragma unroll
    for (int j = 0; j < 4; j++) {
      const int ql = w * 16 + kg * 4 + j;
      const int q = q0 + ql;
      float sv[8]; float tm = -3e38f;
      #pragma unroll
      for (int nf = 0; nf < 8; nf++) {
        const int kv = k0 + nf * 16 + l16;
        const float x = s[nf][j] * C;
        sv[nf] = (!diag || kv <= q) ? x : -3e38f;
        tm = fmaxf(tm, sv[nf]);
      }
      #pragma unroll
      for (int o = 1; o < 16; o <<= 1) tm = fmaxf(tm, __shfl_xor(tm, o));
      const float mn = fmaxf(m_r[j], tm);
      const float scale = exp2f(m_r[j] - mn);
      float ts = 0.f;
      #pragma unroll
      for (int nf = 0; nf < 8; nf++) {
        const float e = exp2f(sv[nf] - mn);
        ts += e;
        lP[(ql << 7) + ((nf * 16 + l16) ^ ((ql & 7) << 3))] = f2bf(e);
      }
      #pragma unroll
      for (int o = 1; o < 16; o <<= 1) ts += __shfl_xor(ts, o);
      l_r[j] = l_r[j] * scale + ts;
      m_r[j] = mn;
      #pragma unroll
      for (int n2 = 0; n2 < 4; n2++) acc_o[n2][j] *= scale;
    }

    // ---- O += P~ V  (P wave-private: rows w*16..w*16+15) ----
    #pragma unroll
    for (int kc = 0; kc < 4; kc++) {
      const int pr = w * 16 + l16;
      short8_t pa = *(const short8_t*)
          &lP[(pr << 7) + ((kc * 32 + kg * 8) ^ ((pr & 7) << 3))];
      #pragma unroll
      for (int n2 = 0; n2 < 4; n2++) {
        short8_t vb = RDSWZ7(lV, n2 * 16 + l16, kc * 64 + kg * 16);
        acc_o[n2] = __builtin_amdgcn_mfma_f32_16x16x32_bf16(pa, vb, acc_o[n2], 0, 0, 0);
      }
    }
    BAR();                 // all waves done with buf cur before its overwrite
  }

  // ---- normalize + write O[b, s, h*64 + hd] ----
  #pragma unroll
  for (int j = 0; j < 4; j++) {
    const int q = q0 + w * 16 + kg * 4 + j;
    const float inv = 1.f / l_r[j];
    #pragma unroll
    for (int n2 = 0; n2 < 4; n2++) {
      const int col = h * HDD + n2 * 16 + l16;
      Og[(((size_t)bidx << 10) + q) * DD + col] = f2bf(acc_o[n2][j] * inv);
    }
  }
}

// ------- LayerNorm (D=1024), src fp32 or bf16, optional residual -------
template<int SRCB16, int ADD_RES, int WRITE_F32>
__global__ __launch_bounds__(256) void k_ln(
    const void* __restrict__ src, const float* __restrict__ res,
    const float* __restrict__ g, const float* __restrict__ b,
    float* __restrict__ of, short* __restrict__ ob) {
  const int row = blockIdx.x;
  const int tid = threadIdx.x;
  float4 v;
  if (SRCB16) {
    short4 s = ((const short4*)src)[((size_t)row << 8) + tid];
    v.x = bf2f(s.x); v.y = bf2f(s.y); v.z = bf2f(s.z); v.w = bf2f(s.w);
  } else {
    v = ((const float4*)src)[((size_t)row << 8) + tid];
  }
  float s1 = v.x + v.y + v.z + v.w;
  float s2 = v.x * v.x + v.y * v.y + v.z * v.z + v.w * v.w;
  #pragma unroll
  for (int o = 32; o; o >>= 1) { s1 += __shfl_xor(s1, o); s2 += __shfl_xor(s2, o); }
  __shared__ float sh1[4], sh2[4];
  if ((tid & 63) == 0) { sh1[tid >> 6] = s1; sh2[tid >> 6] = s2; }
  __syncthreads();
  s1 = sh1[0] + sh1[1] + sh1[2] + sh1[3];
  s2 = sh2[0] + sh2[1] + sh2[2] + sh2[3];
  const float mean = s1 * (1.f / 1024.f);
  const float var  = s2 * (1.f / 1024.f) - mean * mean;
  const float rs = rsqrtf(var + 1e-5f);
  float4 gg = ((const float4*)g)[tid];
  float4 bb = ((const float4*)b)[tid];
  float4 o4;
  o4.x = (v.x - mean) * rs * gg.x + bb.x;
  o4.y = (v.y - mean) * rs * gg.y + bb.y;
  o4.z = (v.z - mean) * rs * gg.z + bb.z;
  o4.w = (v.w - mean) * rs * gg.w + bb.w;
  if (ADD_RES) {
    float4 rr = ((const float4*)(res + ((size_t)row << 10)))[tid];
    o4.x += rr.x; o4.y += rr.y; o4.z += rr.z; o4.w += rr.w;
  }
  if (WRITE_F32) ((float4*)(of + ((size_t)row << 10)))[tid] = o4;
  short4 s4; s4.x = f2bf(o4.x); s4.y = f2bf(o4.y);
  s4.z = f2bf(o4.z); s4.w = f2bf(o4.w);
  ((short4*)ob)[((size_t)row << 8) + tid] = s4;
}

extern "C" void kernel_launch(void* const* d_in, const int* in_sizes, int n_in,
                              void* d_out, int out_size, void* d_ws, size_t ws_size,
                              hipStream_t stream) {
  (void)in_sizes; (void)n_in; (void)out_size; (void)ws_size;
  const int*   tokens  = (const int*)d_in[0];
  const float* tok_emb = (const float*)d_in[1];
  const float* pos_emb = (const float*)d_in[2];
  const float* Wq = (const float*)d_in[3];
  const float* Wk = (const float*)d_in[4];
  const float* Wv = (const float*)d_in[5];
  const float* Wp = (const float*)d_in[6];
  const float* ln1s = (const float*)d_in[7];
  const float* ln1b = (const float*)d_in[8];
  const float* W1 = (const float*)d_in[9];
  const float* b1 = (const float*)d_in[10];
  const float* W2 = (const float*)d_in[11];
  const float* b2 = (const float*)d_in[12];
  const float* ln2s = (const float*)d_in[13];
  const float* ln2b = (const float*)d_in[14];
  const float* lnfs = (const float*)d_in[15];
  const float* lnfb = (const float*)d_in[16];
  const float* Wh = (const float*)d_in[17];
  const float* bh = (const float*)d_in[18];
  float* out = (float*)d_out;

  hipFuncSetAttribute((const void*)k_qkv,
      hipFuncAttributeMaxDynamicSharedMemorySize, 65536);
  hipFuncSetAttribute((const void*)k_ffn1,
      hipFuncAttributeMaxDynamicSharedMemorySize, 65536);
  hipFuncSetAttribute((const void*)k_logits,
      hipFuncAttributeMaxDynamicSharedMemorySize, 131072);
  hipFuncSetAttribute((const void*)k_proj,
      hipFuncAttributeMaxDynamicSharedMemorySize, 65536);
  hipFuncSetAttribute((const void*)k_ffn2,
      hipFuncAttributeMaxDynamicSharedMemorySize, 65536);
  hipFuncSetAttribute((const void*)k_attn,
      hipFuncAttributeMaxDynamicSharedMemorySize, 98304);

  char* p = (char*)d_ws;
  auto alloc = [&](size_t elems, size_t esz) -> char* {
    char* r = p; p += (elems * esz + 255) & ~(size_t)255; return r;
  };
  short* WqkvT = (short*)alloc((size_t)LNUM * 3 * DD * DD, 2);  // [L][3][D][D]
  short* WpT = (short*)alloc((size_t)LNUM * DD * DD, 2);
  short* W1T = (short*)alloc((size_t)LNUM * DD * FF, 2);
  short* W2T = (short*)alloc((size_t)LNUM * DD * FF, 2);
  short* WhT = (short*)alloc((size_t)DD * VV, 2);
  float* xf   = (float*)alloc((size_t)MROWS * DD, 4);   // fp32 residual stream
  short* ffb  = (short*)alloc((size_t)MROWS * DD, 2);   // bf16 GEMM-out for LN
  short* xb   = (short*)alloc((size_t)MROWS * DD, 2);
  short* ab   = (short*)alloc((size_t)MROWS * DD, 2);
  short* qkvb = (short*)alloc((size_t)3 * MROWS * DD, 2); // q | k | v^T contiguous
  short* obuf = (short*)alloc((size_t)MROWS * DD, 2);
  short* hb   = (short*)alloc((size_t)MROWS * FF, 2);
  short* xfb  = (short*)alloc((size_t)MROWS * DD, 2);
  short* qb   = qkvb;
  short* kb   = qkvb + (size_t)MROWS * DD;
  short* vtb  = qkvb + (size_t)2 * MROWS * DD;

  dim3 blk(256);
  const long long DD2 = (long long)DD * DD;
  const long long DF  = (long long)DD * FF;
  // vectorized weight convert+transpose
  k_tcvt4q<<<dim3(16, 16, 3 * LNUM), blk, 0, stream>>>(Wq, Wk, Wv, WqkvT);
  k_tcvt4<<<dim3(16, 16, LNUM), blk, 0, stream>>>(Wp, WpT, DD, DD, DD2, DD2);
  k_tcvt4<<<dim3(64, 16, LNUM), blk, 0, stream>>>(W1, W1T, DD, FF, DF, DF);
  k_tcvt4<<<dim3(16, 64, LNUM), blk, 0, stream>>>(W2, W2T, FF, DD, DF, DF);
  k_tcvt4<<<dim3(500, 16, 1),  blk, 0, stream>>>(Wh, WhT, DD, VV, 0, 0);

  k_embed<<<(MROWS * DD / 4) / 256, blk, 0, stream>>>(tokens, tok_emb, pos_emb, xf, xb);

  for (int l = 0; l < LNUM; l++) {
    const short* wqkv = WqkvT + (size_t)l * 3 * DD * DD;
    const short* wp = WpT + (size_t)l * DD * DD;
    const short* w1 = W1T + (size_t)l * DD * FF;
    const short* w2 = W2T + (size_t)l * DD * FF;

    // fused QKV projection: [4096 x 3072 x 1024]  (dbuf 128^2, natural order)
    k_qkv<<<dim3(24, 32), blk, 65536, stream>>>(xb, wqkv, nullptr, qkvb,
        MROWS, 3 * DD, DD, DD, DD);
    // flash attention v2 -> obuf [B,S,D]
    k_attn<<<dim3(8, BB * HH), 512, 98304, stream>>>(qb, kb, vtb, obuf);
    // proj: [4096 x 1024 x 1024] -> bf16 ffb
    k_proj<<<dim3(8, 32), blk, 65536, stream>>>(obuf, wp, nullptr, ffb,
        MROWS, DD, DD, DD, DD);
    k_ln<1, 1, 0><<<MROWS, blk, 0, stream>>>(ffb, xf, ln1s + (size_t)l * DD,
        ln1b + (size_t)l * DD, nullptr, ab);
    // ffn1: [4096 x 4096 x 1024]  (dbuf 128^2, natural order)
    k_ffn1<<<dim3(32, 32), blk, 65536, stream>>>(ab, w1, b1 + (size_t)l * FF, hb,
        MROWS, FF, DD, DD, DD);
    // ffn2: [4096 x 1024 x 4096] -> bf16 ffb
    k_ffn2<<<dim3(8, 32), blk, 65536, stream>>>(hb, w2, b2 + (size_t)l * DD, ffb,
        MROWS, DD, FF, FF, FF);
    k_ln<1, 1, 1><<<MROWS, blk, 0, stream>>>(ffb, xf, ln2s + (size_t)l * DD,
        ln2b + (size_t)l * DD, xf, xb);
  }

  k_ln<0, 0, 0><<<MROWS, blk, 0, stream>>>(xf, nullptr, lnfs, lnfb, nullptr, xfb);
  // logits = lnf(x) @ Wh + bh : [4096 x 32000 x 1024]  (256^2 8-phase)
  k_logits<<<dim3(VV / 256, 16), 512, 131072, stream>>>(xfb, WhT, bh, out,
      MROWS, VV, DD, DD, DD);
}